// Round 13
// baseline (390.399 us; speedup 1.0000x reference)
//
#include <hip/hip_runtime.h>
#include <hip/hip_bf16.h>

#define N_NODES 50000
#define N_EDGES 800000
#define NBUCKET 196        // NPB=256: bucket = dst>>8, local = dst&255
#define NPB 256
#define BUCKET_CAP 7168
#define PART_EDGES 4096
#define PART_BLOCKS ((N_EDGES + PART_EDGES - 1) / PART_EDGES)  // 196
#define SENTINEL 0xFFFFFFFFu

typedef __attribute__((ext_vector_type(8))) short bf16x8;
typedef __attribute__((ext_vector_type(4))) float f32x4;

__device__ __forceinline__ float bf2f(unsigned short u) {
    unsigned int x = ((unsigned int)u) << 16;
    return __uint_as_float(x);
}
__device__ __forceinline__ unsigned short f2bf(float f) {
    unsigned int x = __float_as_uint(f);
    unsigned int lsb = (x >> 16) & 1u;
    x += 0x7fffu + lsb;
    return (unsigned short)(x >> 16);
}

// ---------------- prep: W fragments + features->bf16 + zero cursor/valid ----------------
#define NF2 ((N_NODES * 64 + 255) / 256)
__global__ __launch_bounds__(256) void k_prep(
        const float* __restrict__ Ws0, const float* __restrict__ Wn0,
        const float* __restrict__ Ws1, const float* __restrict__ Wn1,
        const float* __restrict__ Ws2, const float* __restrict__ Wn2,
        __hip_bfloat16* __restrict__ frag0, __hip_bfloat16* __restrict__ frag1,
        __hip_bfloat16* __restrict__ frag2,
        const float2* __restrict__ fin, unsigned int* __restrict__ fout,
        int* __restrict__ cursor, int* __restrict__ valid) {
    int b = blockIdx.x;
    if (b >= 40 + NF2) {
        int tid = threadIdx.x;
        if (tid < NBUCKET) { cursor[tid] = 0; valid[tid] = 0; }
        return;
    }
    if (b >= 40) {
        int i = (b - 40) * 256 + threadIdx.x;
        if (i < N_NODES * 64) {
            float2 v = fin[i];
            fout[i] = ((unsigned int)f2bf(v.y) << 16) | (unsigned int)f2bf(v.x);
        }
        return;
    }
    const float* Wself;
    const float* Wneigh;
    __hip_bfloat16* frag;
    int Dout, lb;
    if (b < 16)      { Wself = Ws0; Wneigh = Wn0; frag = frag0; Dout = 128; lb = b; }
    else if (b < 32) { Wself = Ws1; Wneigh = Wn1; frag = frag1; Dout = 128; lb = b - 16; }
    else             { Wself = Ws2; Wneigh = Wn2; frag = frag2; Dout = 64;  lb = b - 32; }
    int t = lb * 256 + threadIdx.x;
    int nCt = Dout >> 4;
    int total = nCt * 8 * 64;
    if (t >= total) return;
    int lane = t & 63;
    int kt = (t >> 6) & 7;
    int ct = t >> 9;
    int q = lane >> 4;
    int n = ct * 16 + (lane & 15);
    unsigned short* dstp = (unsigned short*)frag + ((size_t)((ct * 8 + kt) * 64 + lane)) * 8;
    #pragma unroll
    for (int j = 0; j < 8; ++j) {
        int k = kt * 32 + q * 8 + j;
        float v = (k < 128) ? Wself[k * Dout + n] : Wneigh[(k - 128) * Dout + n];
        dstp[j] = f2bf(v);
    }
}

// ---------------- bucketed CSR build v2 (R12-proven: all cross-block runs 64B-aligned) ----------------
__global__ __launch_bounds__(256) void k_partA(const int* __restrict__ src,
                                               const int* __restrict__ dst,
                                               int* __restrict__ cursor,
                                               int* __restrict__ valid,
                                               unsigned int* __restrict__ bucketArr) {
    __shared__ int hist[NBUCKET];
    __shared__ int base[NBUCKET];
    __shared__ int cnt[NBUCKET];
    int tid = threadIdx.x;
    if (tid < NBUCKET) hist[tid] = 0;
    __syncthreads();
    int e0 = blockIdx.x * PART_EDGES;
    for (int j = 0; j < PART_EDGES; j += 256) {
        int e = e0 + j + tid;
        if (e < N_EDGES) atomicAdd(&hist[dst[e] >> 8], 1);
    }
    __syncthreads();
    if (tid < NBUCKET) {
        int h = hist[tid];
        int hp = (h + 15) & ~15;
        int b0 = atomicAdd(&cursor[tid], hp);
        atomicAdd(&valid[tid], h);
        base[tid] = b0;
        cnt[tid] = 0;
        for (int k = h; k < hp; ++k) {
            int p = b0 + k;
            if (p < BUCKET_CAP) bucketArr[(size_t)tid * BUCKET_CAP + p] = SENTINEL;
        }
    }
    __syncthreads();
    for (int j = 0; j < PART_EDGES; j += 256) {
        int e = e0 + j + tid;
        if (e < N_EDGES) {
            int d = dst[e];
            int b = d >> 8;
            int p = base[b] + atomicAdd(&cnt[b], 1);
            if (p < BUCKET_CAP)
                bucketArr[(size_t)b * BUCKET_CAP + p] =
                    (unsigned int)src[e] | ((unsigned int)(d & 255) << 16);
        }
    }
}

__global__ __launch_bounds__(256) void k_scanB(const int* __restrict__ valid,
                                               int* __restrict__ gbase) {
    __shared__ int buf[256];
    int tid = threadIdx.x;
    int v = (tid < NBUCKET) ? valid[tid] : 0;
    int pv = (v + 15) & ~15;
    buf[tid] = pv;
    __syncthreads();
    for (int off = 1; off < 256; off <<= 1) {
        int t = (tid >= off) ? buf[tid - off] : 0;
        __syncthreads();
        buf[tid] += t;
        __syncthreads();
    }
    if (tid < NBUCKET) gbase[tid] = buf[tid] - pv;
}

__global__ __launch_bounds__(256) void k_partB(const unsigned int* __restrict__ bucketArr,
                                               const int* __restrict__ cursor,
                                               const int* __restrict__ gbase,
                                               int* __restrict__ off_beg,
                                               int* __restrict__ off_end,
                                               float* __restrict__ inv_deg,
                                               int* __restrict__ edge_src) {
    __shared__ unsigned int ed[BUCKET_CAP];
    __shared__ int csr[BUCKET_CAP];
    __shared__ int hist[256];
    __shared__ int lbase[256];
    __shared__ int lcnt[256];
    __shared__ int tot_s;
    int b = blockIdx.x;
    int tid = threadIdx.x;
    int size = min(cursor[b], BUCKET_CAP);
    int gb = gbase[b];
    int nbase = b * NPB;
    int ncount = min(NPB, N_NODES - nbase);
    hist[tid] = 0;
    __syncthreads();
    for (int j = 0; j < BUCKET_CAP; j += 256) {
        int i = j + tid;
        if (i < size) {
            unsigned int u = bucketArr[(size_t)b * BUCKET_CAP + i];
            ed[i] = u;
            if ((u >> 16) < 256u) atomicAdd(&hist[u >> 16], 1);
        }
    }
    __syncthreads();
    int v = hist[tid];
    lbase[tid] = v;
    __syncthreads();
    for (int off = 1; off < 256; off <<= 1) {
        int t = (tid >= off) ? lbase[tid - off] : 0;
        __syncthreads();
        lbase[tid] += t;
        __syncthreads();
    }
    int excl = lbase[tid] - v;
    if (tid == 255) tot_s = lbase[255];
    __syncthreads();
    lbase[tid] = excl;
    lcnt[tid] = 0;
    if (tid < ncount) {
        off_beg[nbase + tid] = gb + excl;
        off_end[nbase + tid] = gb + excl + v;
        inv_deg[nbase + tid] = 1.0f / (float)max(v, 1);
    }
    __syncthreads();
    for (int j = 0; j < BUCKET_CAP; j += 256) {
        int i = j + tid;
        if (i < size) {
            unsigned int u = ed[i];
            unsigned int ld = u >> 16;
            if (ld < 256u) {
                int p = lbase[ld] + atomicAdd(&lcnt[ld], 1);
                csr[p] = (int)(u & 0xffffu);
            }
        }
    }
    __syncthreads();
    int tot = tot_s;
    for (int j = 0; j < BUCKET_CAP; j += 256) {
        int i = j + tid;
        if (i < tot) edge_src[gb + i] = csr[i];
    }
}

// ---------------- fused aggregate + GEMM + bias (+ relu + l2norm) ----------------
// Block = 4 waves, 64 nodes. Phase 1: wave wv aggregates nodes wv*16+0..15 into LDS
// (row pitch 136 shorts = 272B: fragment b128 reads hit bank 4*(l15+q)%32 -> all 32
// banks balanced, 8 lanes per 4-bank group). Phase 2: proven MFMA epilogue; A kt<4
// from global h rows, kt>=4 from the LDS msg tile. Kills the msg global round-trip.
template <int NCT, bool LAST>
__global__ __launch_bounds__(256) void k_fused(
        const __hip_bfloat16* __restrict__ hv,
        const int* __restrict__ off_beg, const int* __restrict__ off_end,
        const int* __restrict__ edge_src, const float* __restrict__ inv_deg,
        const __hip_bfloat16* __restrict__ frag, const float* __restrict__ bias,
        void* __restrict__ out_) {
    constexpr int Dout = NCT * 16;
    constexpr int P = 136;  // shorts per lmsg row
    __shared__ short lmsg[64 * P];
    int tid = threadIdx.x;
    int wv = tid >> 6, lane = tid & 63;
    int half = lane >> 5, sub = lane & 31;
    int nblk = blockIdx.x * 64;
    const uint2* hp = (const uint2*)hv;

    // ---- phase 1: aggregate 16 nodes per wave ----
    for (int t = 0; t < 16; ++t) {
        int nloc = wv * 16 + t;
        int node = nblk + nloc;
        float acc[4][4];
        #pragma unroll
        for (int g = 0; g < 4; ++g)
            #pragma unroll
            for (int c = 0; c < 4; ++c) acc[g][c] = 0.f;
        if (node < N_NODES) {
            int beg = off_beg[node], end = off_end[node];
            int i = beg;
            for (; i + 8 <= end; i += 8) {
                int s0 = edge_src[i + half];
                int s1 = edge_src[i + 2 + half];
                int s2 = edge_src[i + 4 + half];
                int s3 = edge_src[i + 6 + half];
                uint2 u0 = hp[(size_t)s0 * 32 + sub];
                uint2 u1 = hp[(size_t)s1 * 32 + sub];
                uint2 u2 = hp[(size_t)s2 * 32 + sub];
                uint2 u3 = hp[(size_t)s3 * 32 + sub];
                acc[0][0] += bf2f((unsigned short)(u0.x & 0xffffu)); acc[0][1] += bf2f((unsigned short)(u0.x >> 16));
                acc[0][2] += bf2f((unsigned short)(u0.y & 0xffffu)); acc[0][3] += bf2f((unsigned short)(u0.y >> 16));
                acc[1][0] += bf2f((unsigned short)(u1.x & 0xffffu)); acc[1][1] += bf2f((unsigned short)(u1.x >> 16));
                acc[1][2] += bf2f((unsigned short)(u1.y & 0xffffu)); acc[1][3] += bf2f((unsigned short)(u1.y >> 16));
                acc[2][0] += bf2f((unsigned short)(u2.x & 0xffffu)); acc[2][1] += bf2f((unsigned short)(u2.x >> 16));
                acc[2][2] += bf2f((unsigned short)(u2.y & 0xffffu)); acc[2][3] += bf2f((unsigned short)(u2.y >> 16));
                acc[3][0] += bf2f((unsigned short)(u3.x & 0xffffu)); acc[3][1] += bf2f((unsigned short)(u3.x >> 16));
                acc[3][2] += bf2f((unsigned short)(u3.y & 0xffffu)); acc[3][3] += bf2f((unsigned short)(u3.y >> 16));
            }
            for (; i + 4 <= end; i += 4) {
                int s0 = edge_src[i + half];
                int s1 = edge_src[i + 2 + half];
                uint2 u0 = hp[(size_t)s0 * 32 + sub];
                uint2 u1 = hp[(size_t)s1 * 32 + sub];
                acc[0][0] += bf2f((unsigned short)(u0.x & 0xffffu)); acc[0][1] += bf2f((unsigned short)(u0.x >> 16));
                acc[0][2] += bf2f((unsigned short)(u0.y & 0xffffu)); acc[0][3] += bf2f((unsigned short)(u0.y >> 16));
                acc[1][0] += bf2f((unsigned short)(u1.x & 0xffffu)); acc[1][1] += bf2f((unsigned short)(u1.x >> 16));
                acc[1][2] += bf2f((unsigned short)(u1.y & 0xffffu)); acc[1][3] += bf2f((unsigned short)(u1.y >> 16));
            }
            for (; i + 2 <= end; i += 2) {
                int s0 = edge_src[i + half];
                uint2 u0 = hp[(size_t)s0 * 32 + sub];
                acc[0][0] += bf2f((unsigned short)(u0.x & 0xffffu)); acc[0][1] += bf2f((unsigned short)(u0.x >> 16));
                acc[0][2] += bf2f((unsigned short)(u0.y & 0xffffu)); acc[0][3] += bf2f((unsigned short)(u0.y >> 16));
            }
            if (i < end && half == 0) {
                int s0 = edge_src[i];
                uint2 u0 = hp[(size_t)s0 * 32 + sub];
                acc[0][0] += bf2f((unsigned short)(u0.x & 0xffffu)); acc[0][1] += bf2f((unsigned short)(u0.x >> 16));
                acc[0][2] += bf2f((unsigned short)(u0.y & 0xffffu)); acc[0][3] += bf2f((unsigned short)(u0.y >> 16));
            }
        }
        float r0 = acc[0][0] + acc[1][0] + acc[2][0] + acc[3][0];
        float r1 = acc[0][1] + acc[1][1] + acc[2][1] + acc[3][1];
        float r2 = acc[0][2] + acc[1][2] + acc[2][2] + acc[3][2];
        float r3 = acc[0][3] + acc[1][3] + acc[2][3] + acc[3][3];
        r0 += __shfl_xor(r0, 32);
        r1 += __shfl_xor(r1, 32);
        r2 += __shfl_xor(r2, 32);
        r3 += __shfl_xor(r3, 32);
        if (half == 0) {
            float w = (node < N_NODES) ? inv_deg[node] : 0.0f;
            uint2 o;
            o.x = ((unsigned int)f2bf(r1 * w) << 16) | (unsigned int)f2bf(r0 * w);
            o.y = ((unsigned int)f2bf(r3 * w) << 16) | (unsigned int)f2bf(r2 * w);
            *(uint2*)&lmsg[nloc * P + 4 * sub] = o;
        }
    }
    __syncthreads();

    // ---- phase 2: MFMA GEMM + epilogue (R12-proven) ----
    int q = lane >> 4, l15 = lane & 15;
    int n0 = nblk + wv * 16;
    int rowA = n0 + l15;
    if (rowA > N_NODES - 1) rowA = N_NODES - 1;  // clamp global loads; stores guarded

    f32x4 gacc[NCT];
    #pragma unroll
    for (int c = 0; c < NCT; ++c) gacc[c] = (f32x4){0.f, 0.f, 0.f, 0.f};

    const bf16x8* fragv = (const bf16x8*)frag;
    #pragma unroll
    for (int kt = 0; kt < 8; ++kt) {
        int kb = (kt & 3) * 32 + q * 8;
        bf16x8 a;
        if (kt < 4) {
            a = *(const bf16x8*)(hv + (size_t)rowA * 128 + kb);
        } else {
            a = *(const bf16x8*)&lmsg[(wv * 16 + l15) * P + kb];
        }
        #pragma unroll
        for (int ct = 0; ct < NCT; ++ct) {
            bf16x8 b = fragv[(ct * 8 + kt) * 64 + lane];
            gacc[ct] = __builtin_amdgcn_mfma_f32_16x16x32_bf16(a, b, gacc[ct], 0, 0, 0);
        }
    }

    float ss[4] = {0.f, 0.f, 0.f, 0.f};
    #pragma unroll
    for (int ct = 0; ct < NCT; ++ct) {
        float bc = bias[ct * 16 + l15];
        #pragma unroll
        for (int r = 0; r < 4; ++r) {
            float v = gacc[ct][r] + bc;
            if (!LAST) v = fmaxf(v, 0.0f);
            gacc[ct][r] = v;
            ss[r] += v * v;
        }
    }

    float scale[4];
    #pragma unroll
    for (int r = 0; r < 4; ++r) {
        if (!LAST) {
            float s = ss[r];
            s += __shfl_xor(s, 1);
            s += __shfl_xor(s, 2);
            s += __shfl_xor(s, 4);
            s += __shfl_xor(s, 8);
            scale[r] = 1.0f / fmaxf(sqrtf(s), 1e-12f);
        } else {
            scale[r] = 1.0f;
        }
    }

    #pragma unroll
    for (int ct = 0; ct < NCT; ++ct) {
        #pragma unroll
        for (int r = 0; r < 4; ++r) {
            int row = n0 + q * 4 + r;
            if (row < N_NODES) {
                float v = gacc[ct][r] * scale[r];
                if (LAST)
                    ((float*)out_)[(size_t)row * Dout + ct * 16 + l15] = v;
                else
                    ((unsigned short*)out_)[(size_t)row * Dout + ct * 16 + l15] = f2bf(v);
            }
        }
    }
}

// ---------------- host launch ----------------

extern "C" void kernel_launch(void* const* d_in, const int* in_sizes, int n_in,
                              void* d_out, int out_size, void* d_ws, size_t ws_size,
                              hipStream_t stream) {
    const float* features = (const float*)d_in[0];
    const int* src = (const int*)d_in[1];
    const int* dst = (const int*)d_in[2];
    const float* Ws0 = (const float*)d_in[3];
    const float* Wn0 = (const float*)d_in[4];
    const float* b0  = (const float*)d_in[5];
    const float* Ws1 = (const float*)d_in[6];
    const float* Wn1 = (const float*)d_in[7];
    const float* b1  = (const float*)d_in[8];
    const float* Ws2 = (const float*)d_in[9];
    const float* Wn2 = (const float*)d_in[10];
    const float* b2  = (const float*)d_in[11];
    float* out = (float*)d_out;

    char* ws = (char*)d_ws;
    size_t off = 0;
    auto alloc = [&](size_t bytes) -> void* {
        void* p = ws + off;
        off = (off + bytes + 255) & ~(size_t)255;
        return p;
    };
    int*   cursor   = (int*)alloc((size_t)NBUCKET * 4);
    int*   valid    = (int*)alloc((size_t)NBUCKET * 4);
    int*   gbase    = (int*)alloc((size_t)NBUCKET * 4);
    unsigned int* bucketArr = (unsigned int*)alloc((size_t)NBUCKET * BUCKET_CAP * 4);
    int*   off_beg  = (int*)alloc((size_t)N_NODES * 4);
    int*   off_end  = (int*)alloc((size_t)N_NODES * 4);
    int*   edge_src = (int*)alloc((size_t)(N_EDGES + NBUCKET * 16) * 4);
    float* inv_deg  = (float*)alloc((size_t)N_NODES * 4);
    __hip_bfloat16* fbf = (__hip_bfloat16*)alloc((size_t)N_NODES * 128 * 2);
    __hip_bfloat16* h1  = (__hip_bfloat16*)alloc((size_t)N_NODES * 128 * 2);
    __hip_bfloat16* h2  = (__hip_bfloat16*)alloc((size_t)N_NODES * 128 * 2);
    __hip_bfloat16* frag0 = (__hip_bfloat16*)alloc((size_t)8 * 8 * 64 * 8 * 2);
    __hip_bfloat16* frag1 = (__hip_bfloat16*)alloc((size_t)8 * 8 * 64 * 8 * 2);
    __hip_bfloat16* frag2 = (__hip_bfloat16*)alloc((size_t)4 * 8 * 64 * 8 * 2);

    // prep (frags + f2bf + counter zero), then bucketed CSR v2 (R12-proven)
    k_prep<<<40 + NF2 + 1, 256, 0, stream>>>(Ws0, Wn0, Ws1, Wn1, Ws2, Wn2,
                                             frag0, frag1, frag2,
                                             (const float2*)features, (unsigned int*)fbf,
                                             cursor, valid);
    k_partA<<<PART_BLOCKS, 256, 0, stream>>>(src, dst, cursor, valid, bucketArr);
    k_scanB<<<1, 256, 0, stream>>>(valid, gbase);
    k_partB<<<NBUCKET, 256, 0, stream>>>(bucketArr, cursor, gbase,
                                         off_beg, off_end, inv_deg, edge_src);

    const int fusedGrid = (N_NODES + 63) / 64;  // 782

    // fused layers (agg + gemm, no msg round-trip)
    k_fused<8, false><<<fusedGrid, 256, 0, stream>>>(fbf, off_beg, off_end, edge_src,
                                                     inv_deg, frag0, b0, h1);
    k_fused<8, false><<<fusedGrid, 256, 0, stream>>>(h1, off_beg, off_end, edge_src,
                                                     inv_deg, frag1, b1, h2);
    k_fused<4, true><<<fusedGrid, 256, 0, stream>>>(h2, off_beg, off_end, edge_src,
                                                    inv_deg, frag2, b2, out);
}